// Round 7
// baseline (450.415 us; speedup 1.0000x reference)
//
#include <hip/hip_runtime.h>
#include <hip/hip_bf16.h>

// Problem constants (BertMultiPooler: B=32, S=4096, H=768, K=64)
// ROUND 7 = MEASUREMENT ROUND: R1 structure, pool x5 internal, gemm x5 dispatches.
#define NB 32
#define NS 4096
#define NH 768
#define NK 64
#define NM (NB * NK)   // 2048 output rows
#define ND (2 * NH)    // 1536 GEMM reduction dim
#define POOL_PASSES 5

typedef short short8 __attribute__((ext_vector_type(8)));
typedef float floatx4 __attribute__((ext_vector_type(4)));

__device__ __forceinline__ unsigned short f2bf(float f) {
    union { float f; unsigned u; } v; v.f = f;
    unsigned r = v.u + 0x7FFFu + ((v.u >> 16) & 1u);   // RNE to bf16
    return (unsigned short)(r >> 16);
}

#define ACC4(s, p) { s.x += p.x; s.y += p.y; s.z += p.z; s.w += p.w; }

// ---------------------------------------------------------------------------
// Kernel 1: build Wc[n][k] (bf16): k<768 -> W_dense[n][k], else W_tab[n][k-768]
// ---------------------------------------------------------------------------
__global__ __launch_bounds__(256) void wconv_kernel(const float* __restrict__ Wd,
                                                    const float* __restrict__ Wt,
                                                    unsigned short* __restrict__ Wc) {
    int i = blockIdx.x * blockDim.x + threadIdx.x;
    const int total = NH * ND / 4;
    if (i >= total) return;
    int e = i * 4;
    int n = e / ND;
    int k = e % ND;
    float4 v = (k < NH) ? *(const float4*)&Wd[n * NH + k]
                        : *(const float4*)&Wt[n * NH + (k - NH)];
    ushort4 o;
    o.x = f2bf(v.x); o.y = f2bf(v.y); o.z = f2bf(v.z); o.w = f2bf(v.w);
    *(ushort4*)&Wc[e] = o;
}

// ---------------------------------------------------------------------------
// Kernel 2 (R1 pool, x POOL_PASSES internal for measurement): segment-mean
// pool + tab gather -> X (bf16, 2048 x 1536). One block per segment,
// 192 threads, 4-deep ping-pong. Each pass recomputes and rewrites the same
// X values (deterministic); asm keep-alive prevents pass collapsing.
// ---------------------------------------------------------------------------
__global__ __launch_bounds__(192) void pool_kernel(const float* __restrict__ hs,
                                                   const int* __restrict__ cls,
                                                   const int* __restrict__ tlen,
                                                   unsigned short* __restrict__ X) {
    const int seg = blockIdx.x;     // 0..2047
    const int b = seg >> 6, k = seg & 63;
    const int start = cls[seg * 2 + 1];
    int end = (k == NK - 1) ? NS : cls[seg * 2 + 3];
    const int tl = tlen[b];
    if (end > tl) end = tl;
    const int cnt = end - start;

    const int t = threadIdx.x;      // owns columns 4t..4t+3
    const float4* base = (const float4*)(hs + ((size_t)b * NS + (size_t)start) * NH) + t;

    for (int pass = 0; pass < POOL_PASSES; ++pass) {
        float4 s0 = {0,0,0,0}, s1 = {0,0,0,0}, s2 = {0,0,0,0}, s3 = {0,0,0,0};
        int r = 0;
        if (cnt >= 4) {
            float4 p0 = base[0 * (NH/4)], p1 = base[1 * (NH/4)],
                   p2 = base[2 * (NH/4)], p3 = base[3 * (NH/4)];
            for (r = 4; r + 4 <= cnt; r += 4) {
                float4 q0 = base[(size_t)(r+0) * (NH/4)];
                float4 q1 = base[(size_t)(r+1) * (NH/4)];
                float4 q2 = base[(size_t)(r+2) * (NH/4)];
                float4 q3 = base[(size_t)(r+3) * (NH/4)];
                ACC4(s0, p0) ACC4(s1, p1) ACC4(s2, p2) ACC4(s3, p3)
                p0 = q0; p1 = q1; p2 = q2; p3 = q3;
            }
            ACC4(s0, p0) ACC4(s1, p1) ACC4(s2, p2) ACC4(s3, p3)
        }
        for (; r < cnt; ++r) {
            float4 v = base[(size_t)r * (NH/4)];
            ACC4(s0, v)
        }
        ACC4(s0, s1) ACC4(s2, s3) ACC4(s0, s2)

        // keep-alive: make s0 opaque so passes can't be proven identical
        asm volatile("" : "+v"(s0.x), "+v"(s0.y), "+v"(s0.z), "+v"(s0.w));

        const float inv = 1.0f / (float)cnt;

        const int tb = cls[seg * 2];
        float4 tv = *((const float4*)(hs + ((size_t)tb * NS + (size_t)start) * NH) + t);

        ushort4 po, ta;
        po.x = f2bf(s0.x * inv); po.y = f2bf(s0.y * inv);
        po.z = f2bf(s0.z * inv); po.w = f2bf(s0.w * inv);
        ta.x = f2bf(tv.x); ta.y = f2bf(tv.y); ta.z = f2bf(tv.z); ta.w = f2bf(tv.w);

        unsigned short* xr = X + (size_t)seg * ND;
        *(ushort4*)&xr[t * 4]      = po;   // pooled half  [0,768)
        *(ushort4*)&xr[NH + t * 4] = ta;   // tab half     [768,1536)
    }
}

// ---------------------------------------------------------------------------
// Kernel 3 (R1 gemm, dispatched x5): out = tanh(X @ Wc^T + b_dense + b_tab)
// M=2048, N=768, K=1536, bf16 MFMA 16x16x32, f32 accumulate.
// Block tile 64x64 (4 waves, 2x2), BK=32. Grid (32, 12). 40-short row pad.
// ---------------------------------------------------------------------------
__global__ __launch_bounds__(256) void gemm_kernel(const unsigned short* __restrict__ X,
                                                   const unsigned short* __restrict__ Wc,
                                                   const float* __restrict__ bd,
                                                   const float* __restrict__ bt,
                                                   float* __restrict__ out) {
    __shared__ unsigned short Al[64 * 40];
    __shared__ unsigned short Bl[64 * 40];

    const int m0 = blockIdx.x * 64;
    const int n0 = blockIdx.y * 64;
    const int tid  = threadIdx.x;
    const int lane = tid & 63;
    const int wv   = tid >> 6;
    const int wr   = wv >> 1;          // wave row (0..1)
    const int wc   = wv & 1;           // wave col (0..1)
    const int lrow = lane & 15;
    const int hi   = lane >> 4;        // 0..3
    const int srow   = tid >> 2;       // staging row 0..63
    const int schunk = tid & 3;        // staging 16B chunk 0..3

    floatx4 acc[2][2] = {};

    const uint4* gA = (const uint4*)(X  + (size_t)(m0 + srow) * ND) + schunk;
    const uint4* gB = (const uint4*)(Wc + (size_t)(n0 + srow) * ND) + schunk;

    uint4 va = gA[0];
    uint4 vb = gB[0];

    const int KT = ND / 32;            // 48
    for (int kt = 0; kt < KT; ++kt) {
        __syncthreads();               // previous iter's ds_reads done
        *(uint4*)&Al[srow * 40 + schunk * 8] = va;
        *(uint4*)&Bl[srow * 40 + schunk * 8] = vb;
        __syncthreads();

        if (kt + 1 < KT) {             // prefetch next tile while MFMAs run
            va = gA[(kt + 1) * 4];
            vb = gB[(kt + 1) * 4];
        }

        short8 a0 = *(const short8*)&Al[(wr * 32 +      lrow) * 40 + hi * 8];
        short8 a1 = *(const short8*)&Al[(wr * 32 + 16 + lrow) * 40 + hi * 8];
        short8 b0 = *(const short8*)&Bl[(wc * 32 +      lrow) * 40 + hi * 8];
        short8 b1 = *(const short8*)&Bl[(wc * 32 + 16 + lrow) * 40 + hi * 8];

        acc[0][0] = __builtin_amdgcn_mfma_f32_16x16x32_bf16(a0, b0, acc[0][0], 0, 0, 0);
        acc[0][1] = __builtin_amdgcn_mfma_f32_16x16x32_bf16(a0, b1, acc[0][1], 0, 0, 0);
        acc[1][0] = __builtin_amdgcn_mfma_f32_16x16x32_bf16(a1, b0, acc[1][0], 0, 0, 0);
        acc[1][1] = __builtin_amdgcn_mfma_f32_16x16x32_bf16(a1, b1, acc[1][1], 0, 0, 0);
    }

    // Epilogue: C/D layout col = lane&15, row = (lane>>4)*4 + reg  [HW-verified]
    for (int mi = 0; mi < 2; ++mi) {
        for (int ni = 0; ni < 2; ++ni) {
            int col  = n0 + wc * 32 + ni * 16 + lrow;
            float bias = bd[col] + bt[col];
            int rowb = m0 + wr * 32 + mi * 16 + hi * 4;
            #pragma unroll
            for (int j = 0; j < 4; ++j) {
                out[(size_t)(rowb + j) * NH + col] = tanhf(acc[mi][ni][j] + bias);
            }
        }
    }
}

// ---------------------------------------------------------------------------
extern "C" void kernel_launch(void* const* d_in, const int* in_sizes, int n_in,
                              void* d_out, int out_size, void* d_ws, size_t ws_size,
                              hipStream_t stream) {
    const float* hs  = (const float*)d_in[0];   // hidden_states (B,S,H) f32
    const float* Wd  = (const float*)d_in[1];   // W_dense (H,H)
    const float* bd  = (const float*)d_in[2];   // b_dense (H,)
    const float* Wt  = (const float*)d_in[3];   // W_tab (H,H)
    const float* bt  = (const float*)d_in[4];   // b_tab (H,)
    const int*   cls = (const int*)d_in[5];     // cls_indexes (B*K, 2) as int32
    const int*   tl  = (const int*)d_in[6];     // table_length (B,) as int32
    float* out = (float*)d_out;

    unsigned short* X  = (unsigned short*)d_ws;          // 2048*1536 bf16 = 6 MB
    unsigned short* Wc = X + (size_t)NM * ND;            // 768*1536 bf16 = 2.25 MB

    // weights convert
    wconv_kernel<<<dim3((NH * ND / 4 + 255) / 256), 256, 0, stream>>>(Wd, Wt, Wc);
    // segment-mean pooling + tab gather  (x5 internal passes for measurement)
    pool_kernel<<<dim3(NM), 192, 0, stream>>>(hs, cls, tl, X);
    // fused GEMM + bias + tanh  (x5 dispatches for measurement)
    gemm_kernel<<<dim3(NM / 64, NH / 64), 256, 0, stream>>>(X, Wc, bd, bt, out);
    gemm_kernel<<<dim3(NM / 64, NH / 64), 256, 0, stream>>>(X, Wc, bd, bt, out);
    gemm_kernel<<<dim3(NM / 64, NH / 64), 256, 0, stream>>>(X, Wc, bd, bt, out);
    gemm_kernel<<<dim3(NM / 64, NH / 64), 256, 0, stream>>>(X, Wc, bd, bt, out);
    gemm_kernel<<<dim3(NM / 64, NH / 64), 256, 0, stream>>>(X, Wc, bd, bt, out);
}

// Round 8
// 121.727 us; speedup vs baseline: 3.7002x; 3.7002x over previous
//
#include <hip/hip_runtime.h>
#include <hip/hip_bf16.h>

// Problem constants (BertMultiPooler: B=32, S=4096, H=768, K=64)
#define NB 32
#define NS 4096
#define NH 768
#define NK 64
#define NM (NB * NK)   // 2048 output rows
#define ND (2 * NH)    // 1536 GEMM reduction dim

// pool geometry: uniform 64-row chunks
#define CSHIFT 6
#define CROWS 64                 // rows per chunk
#define BPB (NS / CROWS)         // 64 chunks per batch
#define PBLOCKS (NB * BPB)       // 2048 pool blocks
#define NSLOT (BPB + 1)          // 65 partial slots per segment
#define WCONV_BLOCKS 384         // appended blocks for weight convert

typedef short short8 __attribute__((ext_vector_type(8)));
typedef float floatx4 __attribute__((ext_vector_type(4)));

__device__ __forceinline__ unsigned short f2bf(float f) {
    union { float f; unsigned u; } v; v.f = f;
    unsigned r = v.u + 0x7FFFu + ((v.u >> 16) & 1u);   // RNE to bf16
    return (unsigned short)(r >> 16);
}

#define ACC4(s, p) { s.x += p.x; s.y += p.y; s.z += p.z; s.w += p.w; }

// ---------------------------------------------------------------------------
// Kernel A: uniform-chunk segment partial sums + fused weight convert.
// Blocks [0,2048): block = one 64-row chunk (192 KB contiguous, uniform).
// 192 threads; thread t owns cols 4t..4t+3. 8-deep register ping-pong ->
// up to 16 float4 loads in flight per lane (probe: does more outstanding
// reads lift the ~3.3 TB/s cold-read rate?). Per segment-run inside the
// chunk, flush one dense f32 partial slot (no atomics):
//   partials[(seg*NSLOT + (chunk - seg_start_chunk))*NH + col]
// Blocks [2048, 2432): bf16 weight convert Wc = [W_dense | W_tab] rows.
// ---------------------------------------------------------------------------
__global__ __launch_bounds__(192) void pool_chunk_kernel(const float* __restrict__ hs,
                                                         const int* __restrict__ cls,
                                                         const int* __restrict__ tlen,
                                                         float* __restrict__ partials,
                                                         const float* __restrict__ Wd,
                                                         const float* __restrict__ Wt,
                                                         unsigned short* __restrict__ Wc) {
    const int bi = blockIdx.x;
    const int t  = threadIdx.x;          // 0..191

    if (bi >= PBLOCKS) {                 // ---- wconv part ----
        const int wb = bi - PBLOCKS;     // 0..383
        #pragma unroll
        for (int j = 0; j < 4; ++j) {
            int i = wb * 768 + j * 192 + t;      // float4 index, < NH*ND/4
            int e = i * 4;
            int n = e / ND;
            int k = e % ND;
            float4 v = (k < NH) ? *(const float4*)&Wd[n * NH + k]
                                : *(const float4*)&Wt[n * NH + (k - NH)];
            ushort4 o;
            o.x = f2bf(v.x); o.y = f2bf(v.y); o.z = f2bf(v.z); o.w = f2bf(v.w);
            *(ushort4*)&Wc[e] = o;
        }
        return;
    }

    // ---- pooling chunk ----
    const int b  = bi >> CSHIFT;         // batch (64 chunks per batch)
    const int ck = bi & (BPB - 1);       // chunk index within batch
    const int r0 = ck << CSHIFT;
    const int tl = tlen[b];
    int r_end = r0 + CROWS;
    if (r_end > tl) r_end = tl;
    if (r0 >= r_end) return;

    // s = upper_bound(pos, r0) - 1 over pos[k] = cls[((b<<6)+k)*2+1]
    int lo = 0, hb = NK;
    while (lo < hb) {
        int mid = (lo + hb) >> 1;
        int p = cls[(((b << 6) + mid) << 1) + 1];
        if (p <= r0) lo = mid + 1; else hb = mid;
    }
    int s = lo - 1;
    int r = r0;
    if (s < 0) {                         // rows before first boundary: invalid
        int p0 = cls[((b << 6) << 1) + 1];
        r = (p0 < r_end) ? p0 : r_end;
        s = 0;
        if (r >= r_end) return;
    }

    const float4* base = (const float4*)(hs + (size_t)b * NS * NH) + t;

    while (r < r_end) {
        int nb = r_end;
        if (s + 1 < NK) {
            int p = cls[(((b << 6) + s + 1) << 1) + 1];
            if (p < nb) nb = p;
        }
        const int n = nb - r;
        const float4* p4 = base + (size_t)r * (NH / 4);

        float4 s0 = {0,0,0,0}, s1 = {0,0,0,0}, s2 = {0,0,0,0}, s3 = {0,0,0,0};
        int i = 0;
        if (n >= 8) {
            float4 p0 = p4[0*(NH/4)], p1 = p4[1*(NH/4)], p2 = p4[2*(NH/4)], p3 = p4[3*(NH/4)];
            float4 a4 = p4[4*(NH/4)], a5 = p4[5*(NH/4)], a6 = p4[6*(NH/4)], a7 = p4[7*(NH/4)];
            for (i = 8; i + 8 <= n; i += 8) {
                float4 q0 = p4[(size_t)(i+0) * (NH/4)];
                float4 q1 = p4[(size_t)(i+1) * (NH/4)];
                float4 q2 = p4[(size_t)(i+2) * (NH/4)];
                float4 q3 = p4[(size_t)(i+3) * (NH/4)];
                float4 q4 = p4[(size_t)(i+4) * (NH/4)];
                float4 q5 = p4[(size_t)(i+5) * (NH/4)];
                float4 q6 = p4[(size_t)(i+6) * (NH/4)];
                float4 q7 = p4[(size_t)(i+7) * (NH/4)];
                ACC4(s0, p0) ACC4(s1, p1) ACC4(s2, p2) ACC4(s3, p3)
                ACC4(s0, a4) ACC4(s1, a5) ACC4(s2, a6) ACC4(s3, a7)
                p0 = q0; p1 = q1; p2 = q2; p3 = q3;
                a4 = q4; a5 = q5; a6 = q6; a7 = q7;
            }
            ACC4(s0, p0) ACC4(s1, p1) ACC4(s2, p2) ACC4(s3, p3)
            ACC4(s0, a4) ACC4(s1, a5) ACC4(s2, a6) ACC4(s3, a7)
        }
        for (; i < n; ++i) {
            float4 v = p4[(size_t)i * (NH/4)];
            ACC4(s0, v)
        }
        ACC4(s0, s1) ACC4(s2, s3) ACC4(s0, s2)

        const int start_s = cls[(((b << 6) + s) << 1) + 1];
        const int slot = ck - (start_s >> CSHIFT);            // 0..NSLOT-1
        *(float4*)&partials[((size_t)((b << 6) + s) * NSLOT + slot) * NH + (t << 2)] = s0;

        r = nb;
        ++s;
    }
}

// ---------------------------------------------------------------------------
// Kernel B: finalize -> X (bf16, 2048 x 1536): sum slots, mean | tab gather
// ---------------------------------------------------------------------------
__global__ __launch_bounds__(192) void finalize_kernel(const float* __restrict__ hs,
                                                       const float* __restrict__ partials,
                                                       const int* __restrict__ cls,
                                                       const int* __restrict__ tlen,
                                                       unsigned short* __restrict__ X) {
    const int seg = blockIdx.x;
    const int c   = threadIdx.x;
    const int b = seg >> 6, k = seg & 63;
    const int start = cls[seg * 2 + 1];
    int end = (k == NK - 1) ? NS : cls[seg * 2 + 3];
    const int tl = tlen[b];
    if (end > tl) end = tl;
    const int cnt = end - start;

    const int nslots = ((end - 1) >> CSHIFT) - (start >> CSHIFT) + 1;  // >=1 for cnt>=1

    float4 s = {0,0,0,0};
    for (int q = 0; q < nslots; ++q) {
        float4 p = *(const float4*)&partials[((size_t)seg * NSLOT + q) * NH + c * 4];
        ACC4(s, p)
    }
    const float inv = 1.0f / (float)cnt;

    const int tb = cls[seg * 2];
    float4 tv = *((const float4*)(hs + ((size_t)tb * NS + start) * NH) + c);

    ushort4 po, ta;
    po.x = f2bf(s.x * inv); po.y = f2bf(s.y * inv);
    po.z = f2bf(s.z * inv); po.w = f2bf(s.w * inv);
    ta.x = f2bf(tv.x); ta.y = f2bf(tv.y); ta.z = f2bf(tv.z); ta.w = f2bf(tv.w);

    unsigned short* xr = X + (size_t)seg * ND;
    *(ushort4*)&xr[c * 4]      = po;   // pooled half  [0,768)
    *(ushort4*)&xr[NH + c * 4] = ta;   // tab half     [768,1536)
}

// ---------------------------------------------------------------------------
// Kernel C: out = tanh(X @ Wc^T + b_dense + b_tab)
// M=2048, N=768, K=1536, bf16 MFMA 16x16x32, f32 accumulate.
// Block tile 64x64 (4 waves, 2x2), BK=32. Grid (32, 12). 40-short row pad.
// ---------------------------------------------------------------------------
__global__ __launch_bounds__(256) void gemm_kernel(const unsigned short* __restrict__ X,
                                                   const unsigned short* __restrict__ Wc,
                                                   const float* __restrict__ bd,
                                                   const float* __restrict__ bt,
                                                   float* __restrict__ out) {
    __shared__ unsigned short Al[64 * 40];
    __shared__ unsigned short Bl[64 * 40];

    const int m0 = blockIdx.x * 64;
    const int n0 = blockIdx.y * 64;
    const int tid  = threadIdx.x;
    const int lane = tid & 63;
    const int wv   = tid >> 6;
    const int wr   = wv >> 1;          // wave row (0..1)
    const int wc   = wv & 1;           // wave col (0..1)
    const int lrow = lane & 15;
    const int hi   = lane >> 4;        // 0..3
    const int srow   = tid >> 2;       // staging row 0..63
    const int schunk = tid & 3;        // staging 16B chunk 0..3

    floatx4 acc[2][2] = {};

    const uint4* gA = (const uint4*)(X  + (size_t)(m0 + srow) * ND) + schunk;
    const uint4* gB = (const uint4*)(Wc + (size_t)(n0 + srow) * ND) + schunk;

    uint4 va = gA[0];
    uint4 vb = gB[0];

    const int KT = ND / 32;            // 48
    for (int kt = 0; kt < KT; ++kt) {
        __syncthreads();               // previous iter's ds_reads done
        *(uint4*)&Al[srow * 40 + schunk * 8] = va;
        *(uint4*)&Bl[srow * 40 + schunk * 8] = vb;
        __syncthreads();

        if (kt + 1 < KT) {             // prefetch next tile while MFMAs run
            va = gA[(kt + 1) * 4];
            vb = gB[(kt + 1) * 4];
        }

        short8 a0 = *(const short8*)&Al[(wr * 32 +      lrow) * 40 + hi * 8];
        short8 a1 = *(const short8*)&Al[(wr * 32 + 16 + lrow) * 40 + hi * 8];
        short8 b0 = *(const short8*)&Bl[(wc * 32 +      lrow) * 40 + hi * 8];
        short8 b1 = *(const short8*)&Bl[(wc * 32 + 16 + lrow) * 40 + hi * 8];

        acc[0][0] = __builtin_amdgcn_mfma_f32_16x16x32_bf16(a0, b0, acc[0][0], 0, 0, 0);
        acc[0][1] = __builtin_amdgcn_mfma_f32_16x16x32_bf16(a0, b1, acc[0][1], 0, 0, 0);
        acc[1][0] = __builtin_amdgcn_mfma_f32_16x16x32_bf16(a1, b0, acc[1][0], 0, 0, 0);
        acc[1][1] = __builtin_amdgcn_mfma_f32_16x16x32_bf16(a1, b1, acc[1][1], 0, 0, 0);
    }

    // Epilogue: C/D layout col = lane&15, row = (lane>>4)*4 + reg  [HW-verified]
    for (int mi = 0; mi < 2; ++mi) {
        for (int ni = 0; ni < 2; ++ni) {
            int col  = n0 + wc * 32 + ni * 16 + lrow;
            float bias = bd[col] + bt[col];
            int rowb = m0 + wr * 32 + mi * 16 + hi * 4;
            #pragma unroll
            for (int j = 0; j < 4; ++j) {
                out[(size_t)(rowb + j) * NH + col] = tanhf(acc[mi][ni][j] + bias);
            }
        }
    }
}

// ---------------------------------------------------------------------------
extern "C" void kernel_launch(void* const* d_in, const int* in_sizes, int n_in,
                              void* d_out, int out_size, void* d_ws, size_t ws_size,
                              hipStream_t stream) {
    const float* hs  = (const float*)d_in[0];   // hidden_states (B,S,H) f32
    const float* Wd  = (const float*)d_in[1];   // W_dense (H,H)
    const float* bd  = (const float*)d_in[2];   // b_dense (H,)
    const float* Wt  = (const float*)d_in[3];   // W_tab (H,H)
    const float* bt  = (const float*)d_in[4];   // b_tab (H,)
    const int*   cls = (const int*)d_in[5];     // cls_indexes (B*K, 2) as int32
    const int*   tl  = (const int*)d_in[6];     // table_length (B,) as int32
    float* out = (float*)d_out;

    // ws layout: [partials f32 2048*65*768 = 409 MB] [Wc bf16] [X bf16]
    float*          partials = (float*)d_ws;
    unsigned short* Wc = (unsigned short*)(partials + (size_t)NM * NSLOT * NH);
    unsigned short* X  = Wc + (size_t)NH * ND;

    // uniform-chunk partial sums + fused weight convert
    pool_chunk_kernel<<<dim3(PBLOCKS + WCONV_BLOCKS), 192, 0, stream>>>(
        hs, cls, tl, partials, Wd, Wt, Wc);
    // finalize: combine slots, mean, tab gather, pack X (bf16)
    finalize_kernel<<<dim3(NM), 192, 0, stream>>>(hs, partials, cls, tl, X);
    // fused GEMM + bias + tanh
    gemm_kernel<<<dim3(NM / 64, NH / 64), 256, 0, stream>>>(X, Wc, bd, bt, out);
}